// Round 12
// baseline (172.881 us; speedup 1.0000x reference)
//
#include <hip/hip_runtime.h>
#include <stdint.h>

// EdgeConv B=256,N=128,C=64,K=16 — round 13: restructured KNN (8 rows/wave).
// R12 lesson: ws poison-fills are UNCONDITIONAL (~84us fixed); controllable
// = knn (~25-30us) + mlp (42us) + gaps. This round: knn iterated per wave —
// batch points staged in LDS once, per-lane pj/rj hoisted (was recomputed
// per row: ~3x VALU cut), 1024 blocks x 4 waves x 8 rows. Same exact-tie
// rank-count math (bitwise identical dists). R10-style lgkm fences around
// the keys_s reuse. DIAGNOSTIC: this is the fused kernels' KNN structure
// isolated against the proven mlp — pass => R9/R10 bug elsewhere; fail =>
// structure is the bug, revert to R12. mlp + out-stash unchanged from R12.

#define KK 16
#define EPSV 1e-3f
#define SW0 136  // w0T stride (128 k-cols + 8 pad, ushorts)
#define SW 72    // 64 + 8

#define LDS_FENCE()                                     \
  do {                                                  \
    asm volatile("s_waitcnt lgkmcnt(0)" ::: "memory");  \
    __builtin_amdgcn_sched_barrier(0);                  \
  } while (0)

typedef __bf16 bf16x8 __attribute__((ext_vector_type(8)));
typedef float f32x4 __attribute__((ext_vector_type(4)));
union B8 { uint4 u; bf16x8 v; };

__device__ __forceinline__ unsigned int f2ord(float f) {
  unsigned int u = __float_as_uint(f);
  return (u & 0x80000000u) ? ~u : (u | 0x80000000u);
}
__device__ __forceinline__ unsigned short f2bs(float f) {
  __bf16 b = (__bf16)f;  // RNE fptrunc
  return __builtin_bit_cast(unsigned short, b);
}
__device__ __forceinline__ unsigned int pk(float lo, float hi) {
  return (unsigned int)f2bs(lo) | ((unsigned int)f2bs(hi) << 16);
}

__global__ __launch_bounds__(256) void knn_kernel(const float* __restrict__ pts,
                                                  int* __restrict__ knn) {
  __shared__ __align__(16) unsigned long long keys[4][128];
  __shared__ __align__(16) float2 pts_s[128];
  const int tid = threadIdx.x;
  const int wv = tid >> 6;
  const int lane = tid & 63;
  const int b = blockIdx.x >> 2;                     // batch
  const int nbase = (blockIdx.x & 3) * 32 + wv * 8;  // this wave's 8 rows

  if (tid < 64) {
    const float4 p4 = ((const float4*)(pts + b * 256))[tid];
    *(float4*)&pts_s[2 * tid] = p4;
  }
  __syncthreads();

  // hoisted per-lane neighbor-point terms (was recomputed every row)
  const float2 pj0 = pts_s[lane];
  const float2 pj1 = pts_s[lane + 64];
  const float rj0 = __fadd_rn(__fmul_rn(pj0.x, pj0.x), __fmul_rn(pj0.y, pj0.y));
  const float rj1 = __fadd_rn(__fmul_rn(pj1.x, pj1.x), __fmul_rn(pj1.y, pj1.y));

  for (int r = 0; r < 8; ++r) {
    const int n = nbase + r;
    const float2 pn = pts_s[n];
    const float rn = __fadd_rn(__fmul_rn(pn.x, pn.x), __fmul_rn(pn.y, pn.y));
    const float dot0 = __fadd_rn(__fmul_rn(pn.x, pj0.x), __fmul_rn(pn.y, pj0.y));
    const float dot1 = __fadd_rn(__fmul_rn(pn.x, pj1.x), __fmul_rn(pn.y, pj1.y));
    const float d0 = __fadd_rn(__fsub_rn(rn, __fmul_rn(2.0f, dot0)), rj0);
    const float d1 = __fadd_rn(__fsub_rn(rn, __fmul_rn(2.0f, dot1)), rj1);
    const unsigned long long key0 =
        ((unsigned long long)f2ord(d0) << 32) | (unsigned int)lane;
    const unsigned long long key1 =
        ((unsigned long long)f2ord(d1) << 32) | (unsigned int)(lane + 64);
    LDS_FENCE();  // prior iteration's key reads fully drained
    keys[wv][lane] = key0;
    keys[wv][lane + 64] = key1;
    LDS_FENCE();  // this iteration's key writes published
    int c0 = 0, c1 = 0;
#pragma unroll 8
    for (int j = 0; j < 128; j += 2) {
      const ulonglong2 kp = *(const ulonglong2*)&keys[wv][j];
      c0 += (kp.x < key0); c0 += (kp.y < key0);
      c1 += (kp.x < key1); c1 += (kp.y < key1);
    }
    // rank 0 = self (dropped); ranks 1..16 kept.
    // out-stash layout: block (row>>6)'s region, slot (row&63)*KK + rank-1
    const int row = b * 128 + n;
    const int base = (row >> 6) * 4096 + (row & 63) * KK;
    if (c0 >= 1 && c0 <= 16) knn[base + c0 - 1] = lane;
    if (c1 >= 1 && c1 <= 16) knn[base + c1 - 1] = lane + 64;
  }
}

__global__ __launch_bounds__(256) void mlp_kernel(
    const float* __restrict__ feat, const int* knnIdx,
    const float* __restrict__ w0, const float* __restrict__ g0,
    const float* __restrict__ b0, const float* __restrict__ m0,
    const float* __restrict__ v0, const float* __restrict__ w1,
    const float* __restrict__ g1, const float* __restrict__ b1,
    const float* __restrict__ m1, const float* __restrict__ v1,
    const float* __restrict__ w2, const float* __restrict__ g2,
    const float* __restrict__ b2, const float* __restrict__ m2,
    const float* __restrict__ v2, const float* __restrict__ wsc,
    const float* __restrict__ gsc, const float* __restrict__ bsc,
    const float* __restrict__ msc, const float* __restrict__ vsc,
    float* out) {
  __shared__ __align__(16) unsigned short w0T[64 * SW0];   // [cout][cin] bf16
  __shared__ __align__(16) unsigned short w1T[64 * SW];
  __shared__ __align__(16) unsigned short w2T[64 * SW];
  __shared__ __align__(16) unsigned short wscT[64 * SW];
  __shared__ __align__(16) unsigned short X0[4][2][16 * SW];  // 2 tiles/wave

  const int tid = threadIdx.x;
  const int wv = tid >> 6;       // 4 waves
  const int lane = tid & 63;
  const int m = lane & 15;   // MFMA m/n within tile
  const int q4 = lane >> 4;  // MFMA quad

  // ---- preload knn indices for all 16 rows (from this block's out region;
  //      issued before __syncthreads so loads drain before any out store) ----
  const int row0 = blockIdx.x * 64 + wv * 16;  // this wave's 16 rows
  const int kk = lane >> 2, pp = lane & 3;
  int jdx[16];
#pragma unroll
  for (int rr = 0; rr < 16; ++rr)
    jdx[rr] = knnIdx[blockIdx.x * 4096 + (wv * 16 + rr) * KK + kk];

  // ---- stage weights transposed to bf16 (once per block) ----
#pragma unroll
  for (int q = 0; q < 8; ++q) {
    const int v = tid + 256 * q;           // float4 idx, 2048 total
    const float4 w = ((const float4*)w0)[v];
    const int i = v >> 4, c = (v & 15) << 2;
    w0T[(c + 0) * SW0 + i] = f2bs(w.x);
    w0T[(c + 1) * SW0 + i] = f2bs(w.y);
    w0T[(c + 2) * SW0 + i] = f2bs(w.z);
    w0T[(c + 3) * SW0 + i] = f2bs(w.w);
  }
#pragma unroll
  for (int q = 0; q < 4; ++q) {
    const int v = tid + 256 * q;           // 1024 total each
    const int i = v >> 4, c = (v & 15) << 2;
    float4 w = ((const float4*)w1)[v];
    w1T[(c + 0) * SW + i] = f2bs(w.x);
    w1T[(c + 1) * SW + i] = f2bs(w.y);
    w1T[(c + 2) * SW + i] = f2bs(w.z);
    w1T[(c + 3) * SW + i] = f2bs(w.w);
    w = ((const float4*)w2)[v];
    w2T[(c + 0) * SW + i] = f2bs(w.x);
    w2T[(c + 1) * SW + i] = f2bs(w.y);
    w2T[(c + 2) * SW + i] = f2bs(w.z);
    w2T[(c + 3) * SW + i] = f2bs(w.w);
    w = ((const float4*)wsc)[v];
    wscT[(c + 0) * SW + i] = f2bs(w.x);
    wscT[(c + 1) * SW + i] = f2bs(w.y);
    wscT[(c + 2) * SW + i] = f2bs(w.z);
    wscT[(c + 3) * SW + i] = f2bs(w.w);
  }

  // ---- folded BN affine, this lane's channel per n-tile: c = nt*16+m ----
  float s0[4], o0[4], s1[4], o1[4], s2[4], o2[4], ssc[4], osc[4];
#pragma unroll
  for (int nt = 0; nt < 4; ++nt) {
    const int c = nt * 16 + m;
    float s;
    s = g0[c] / sqrtf(v0[c] + EPSV); s0[nt] = s; o0[nt] = b0[c] - m0[c] * s;
    s = g1[c] / sqrtf(v1[c] + EPSV); s1[nt] = s; o1[nt] = b1[c] - m1[c] * s;
    s = g2[c] / sqrtf(v2[c] + EPSV); s2[nt] = s; o2[nt] = b2[c] - m2[c] * s;
    s = gsc[c] / sqrtf(vsc[c] + EPSV); ssc[nt] = s; osc[nt] = bsc[c] - msc[c] * s;
  }

  // ---- stage this wave's 16 center rows as bf16 into X0[wv][0] ----
  {
    const int r = lane >> 2, p = lane & 3;
    const float4* fr = (const float4*)(feat + (row0 + r) * 64);
    const float4 a = fr[p * 4 + 0], bq = fr[p * 4 + 1];
    const float4 cq = fr[p * 4 + 2], dq = fr[p * 4 + 3];
    uint4 u0, u1;
    u0.x = pk(a.x, a.y); u0.y = pk(a.z, a.w);
    u0.z = pk(bq.x, bq.y); u0.w = pk(bq.z, bq.w);
    u1.x = pk(cq.x, cq.y); u1.y = pk(cq.z, cq.w);
    u1.z = pk(dq.x, dq.y); u1.w = pk(dq.z, dq.w);
    *(uint4*)&X0[wv][0][r * SW + p * 16] = u0;
    *(uint4*)&X0[wv][0][r * SW + p * 16 + 8] = u1;
  }

  const float* featb = feat + (row0 >> 7) * (128 * 64);  // batch base

  // ---- prefetch rows 0,1 neighbor features (packed to bf16 on arrival) ----
  uint4 uA0, uA1, uB0, uB1;
  {
    const float4* np_ = (const float4*)(featb + jdx[0] * 64);
    const float4 n0 = np_[pp * 4 + 0], n1 = np_[pp * 4 + 1];
    const float4 n2 = np_[pp * 4 + 2], n3 = np_[pp * 4 + 3];
    uA0.x = pk(n0.x, n0.y); uA0.y = pk(n0.z, n0.w);
    uA0.z = pk(n1.x, n1.y); uA0.w = pk(n1.z, n1.w);
    uA1.x = pk(n2.x, n2.y); uA1.y = pk(n2.z, n2.w);
    uA1.z = pk(n3.x, n3.y); uA1.w = pk(n3.z, n3.w);
  }
  {
    const float4* np_ = (const float4*)(featb + jdx[1] * 64);
    const float4 n0 = np_[pp * 4 + 0], n1 = np_[pp * 4 + 1];
    const float4 n2 = np_[pp * 4 + 2], n3 = np_[pp * 4 + 3];
    uB0.x = pk(n0.x, n0.y); uB0.y = pk(n0.z, n0.w);
    uB0.z = pk(n1.x, n1.y); uB0.w = pk(n1.z, n1.w);
    uB1.x = pk(n2.x, n2.y); uB1.y = pk(n2.z, n2.w);
    uB1.z = pk(n3.x, n3.y); uB1.w = pk(n3.z, n3.w);
  }

  __syncthreads();  // weights visible; all waves' jdx loads drained

  // ---- prelim GEMMs over centers: shortcut (wsc), w0-top, w0-bot ----
  const f32x4 fzero = {0.f, 0.f, 0.f, 0.f};
  f32x4 sacc[4] = {fzero, fzero, fzero, fzero};
  f32x4 ctp[4] = {fzero, fzero, fzero, fzero};
  f32x4 cbt[4] = {fzero, fzero, fzero, fzero};
#pragma unroll
  for (int t = 0; t < 2; ++t) {
    B8 af; af.u = *(const uint4*)&X0[wv][0][m * SW + t * 32 + q4 * 8];
#pragma unroll
    for (int nt = 0; nt < 4; ++nt) {
      B8 bs, bt, bb;
      bs.u = *(const uint4*)&wscT[(nt * 16 + m) * SW + t * 32 + q4 * 8];
      bt.u = *(const uint4*)&w0T[(nt * 16 + m) * SW0 + t * 32 + q4 * 8];
      bb.u = *(const uint4*)&w0T[(nt * 16 + m) * SW0 + 64 + t * 32 + q4 * 8];
      sacc[nt] = __builtin_amdgcn_mfma_f32_16x16x32_bf16(af.v, bs.v, sacc[nt], 0, 0, 0);
      ctp[nt]  = __builtin_amdgcn_mfma_f32_16x16x32_bf16(af.v, bt.v, ctp[nt], 0, 0, 0);
      cbt[nt]  = __builtin_amdgcn_mfma_f32_16x16x32_bf16(af.v, bb.v, cbt[nt], 0, 0, 0);
    }
  }
  // scf: BN'd shortcut; ct: center@(Wtop-Wbot), row = q4*4+reg, ch = nt*16+m
  float scf[4][4], ct[4][4];
#pragma unroll
  for (int nt = 0; nt < 4; ++nt)
#pragma unroll
    for (int r = 0; r < 4; ++r) {
      scf[nt][r] = fmaf(sacc[nt][r], ssc[nt], osc[nt]);
      ct[nt][r] = ctp[nt][r] - cbt[nt][r];
    }

  // ---- 8 iterations x 2 rows (static reg indexing throughout) ----
#pragma unroll
  for (int rp = 0; rp < 8; ++rp) {
    const int qo = rp >> 1;                 // = rowA>>2 = rowB>>2
    const int riA = (2 * rp) & 3, riB = (2 * rp + 1) & 3;
    const int rowA = row0 + 2 * rp, rowB = rowA + 1;

    // stage both rows' neighbors (prefetched, already bf16-packed)
    *(uint4*)&X0[wv][0][kk * SW + pp * 16] = uA0;
    *(uint4*)&X0[wv][0][kk * SW + pp * 16 + 8] = uA1;
    *(uint4*)&X0[wv][1][kk * SW + pp * 16] = uB0;
    *(uint4*)&X0[wv][1][kk * SW + pp * 16 + 8] = uB1;

    // prefetch next row pair (hidden under this pair's MFMAs)
    if (rp < 7) {
      {
        const float4* np_ = (const float4*)(featb + jdx[2 * rp + 2] * 64);
        const float4 n0 = np_[pp * 4 + 0], n1 = np_[pp * 4 + 1];
        const float4 n2 = np_[pp * 4 + 2], n3 = np_[pp * 4 + 3];
        uA0.x = pk(n0.x, n0.y); uA0.y = pk(n0.z, n0.w);
        uA0.z = pk(n1.x, n1.y); uA0.w = pk(n1.z, n1.w);
        uA1.x = pk(n2.x, n2.y); uA1.y = pk(n2.z, n2.w);
        uA1.z = pk(n3.x, n3.y); uA1.w = pk(n3.z, n3.w);
      }
      {
        const float4* np_ = (const float4*)(featb + jdx[2 * rp + 3] * 64);
        const float4 n0 = np_[pp * 4 + 0], n1 = np_[pp * 4 + 1];
        const float4 n2 = np_[pp * 4 + 2], n3 = np_[pp * 4 + 3];
        uB0.x = pk(n0.x, n0.y); uB0.y = pk(n0.z, n0.w);
        uB0.z = pk(n1.x, n1.y); uB0.w = pk(n1.z, n1.w);
        uB1.x = pk(n2.x, n2.y); uB1.y = pk(n2.z, n2.w);
        uB1.z = pk(n3.x, n3.y); uB1.w = pk(n3.z, n3.w);
      }
    }

    // ---- layer 0: acc = centerTerm(row) + nbr @ w0_bot (K=64) ----
    f32x4 accA[4], accB[4];
#pragma unroll
    for (int nt = 0; nt < 4; ++nt) {
      const float cA = __shfl(ct[nt][riA], qo * 16 + m);
      const float cB = __shfl(ct[nt][riB], qo * 16 + m);
      f32x4 a; a[0] = cA; a[1] = cA; a[2] = cA; a[3] = cA;
      accA[nt] = a;
      f32x4 b; b[0] = cB; b[1] = cB; b[2] = cB; b[3] = cB;
      accB[nt] = b;
    }
#pragma unroll
    for (int t = 0; t < 2; ++t) {
      B8 afA, afB;
      afA.u = *(const uint4*)&X0[wv][0][m * SW + t * 32 + q4 * 8];
      afB.u = *(const uint4*)&X0[wv][1][m * SW + t * 32 + q4 * 8];
#pragma unroll
      for (int nt = 0; nt < 4; ++nt) {
        B8 bf_; bf_.u = *(const uint4*)&w0T[(nt * 16 + m) * SW0 + 64 + t * 32 + q4 * 8];
        accA[nt] = __builtin_amdgcn_mfma_f32_16x16x32_bf16(afA.v, bf_.v, accA[nt], 0, 0, 0);
        accB[nt] = __builtin_amdgcn_mfma_f32_16x16x32_bf16(afB.v, bf_.v, accB[nt], 0, 0, 0);
      }
    }
#pragma unroll
    for (int nt = 0; nt < 4; ++nt)
#pragma unroll
      for (int r2 = 0; r2 < 4; ++r2) {
        const float yA = fmaxf(fmaf(accA[nt][r2], s0[nt], o0[nt]), 0.f);
        const float yB = fmaxf(fmaf(accB[nt][r2], s0[nt], o0[nt]), 0.f);
        X0[wv][0][(q4 * 4 + r2) * SW + nt * 16 + m] = f2bs(yA);
        X0[wv][1][(q4 * 4 + r2) * SW + nt * 16 + m] = f2bs(yB);
      }

    // ---- layer 1: K=64 (in-place, in-wave DS ordering) ----
#pragma unroll
    for (int nt = 0; nt < 4; ++nt) { accA[nt] = fzero; accB[nt] = fzero; }
#pragma unroll
    for (int t = 0; t < 2; ++t) {
      B8 afA, afB;
      afA.u = *(const uint4*)&X0[wv][0][m * SW + t * 32 + q4 * 8];
      afB.u = *(const uint4*)&X0[wv][1][m * SW + t * 32 + q4 * 8];
#pragma unroll
      for (int nt = 0; nt < 4; ++nt) {
        B8 bf_; bf_.u = *(const uint4*)&w1T[(nt * 16 + m) * SW + t * 32 + q4 * 8];
        accA[nt] = __builtin_amdgcn_mfma_f32_16x16x32_bf16(afA.v, bf_.v, accA[nt], 0, 0, 0);
        accB[nt] = __builtin_amdgcn_mfma_f32_16x16x32_bf16(afB.v, bf_.v, accB[nt], 0, 0, 0);
      }
    }
#pragma unroll
    for (int nt = 0; nt < 4; ++nt)
#pragma unroll
      for (int r2 = 0; r2 < 4; ++r2) {
        const float yA = fmaxf(fmaf(accA[nt][r2], s1[nt], o1[nt]), 0.f);
        const float yB = fmaxf(fmaf(accB[nt][r2], s1[nt], o1[nt]), 0.f);
        X0[wv][0][(q4 * 4 + r2) * SW + nt * 16 + m] = f2bs(yA);
        X0[wv][1][(q4 * 4 + r2) * SW + nt * 16 + m] = f2bs(yB);
      }

    // ---- layer 2: K=64 ----
#pragma unroll
    for (int nt = 0; nt < 4; ++nt) { accA[nt] = fzero; accB[nt] = fzero; }
#pragma unroll
    for (int t = 0; t < 2; ++t) {
      B8 afA, afB;
      afA.u = *(const uint4*)&X0[wv][0][m * SW + t * 32 + q4 * 8];
      afB.u = *(const uint4*)&X0[wv][1][m * SW + t * 32 + q4 * 8];
#pragma unroll
      for (int nt = 0; nt < 4; ++nt) {
        B8 bf_; bf_.u = *(const uint4*)&w2T[(nt * 16 + m) * SW + t * 32 + q4 * 8];
        accA[nt] = __builtin_amdgcn_mfma_f32_16x16x32_bf16(afA.v, bf_.v, accA[nt], 0, 0, 0);
        accB[nt] = __builtin_amdgcn_mfma_f32_16x16x32_bf16(afB.v, bf_.v, accB[nt], 0, 0, 0);
      }
    }

    // ---- BN+ReLU, mean over k, add shortcut, store both rows ----
    float poolA[4], poolB[4];
#pragma unroll
    for (int nt = 0; nt < 4; ++nt) {
      float pa = 0.f, pb2 = 0.f;
#pragma unroll
      for (int r2 = 0; r2 < 4; ++r2) {
        pa += fmaxf(fmaf(accA[nt][r2], s2[nt], o2[nt]), 0.f);
        pb2 += fmaxf(fmaf(accB[nt][r2], s2[nt], o2[nt]), 0.f);
      }
      pa += __shfl_xor(pa, 16);
      pa += __shfl_xor(pa, 32);
      poolA[nt] = pa * 0.0625f;
      pb2 += __shfl_xor(pb2, 16);
      pb2 += __shfl_xor(pb2, 32);
      poolB[nt] = pb2 * 0.0625f;
    }
    if (q4 == qo) {
#pragma unroll
      for (int nt = 0; nt < 4; ++nt) {
        out[rowA * 64 + nt * 16 + m] = fmaxf(scf[nt][riA] + poolA[nt], 0.f);
        out[rowB * 64 + nt * 16 + m] = fmaxf(scf[nt][riB] + poolB[nt], 0.f);
      }
    }
  }
}

extern "C" void kernel_launch(void* const* d_in, const int* in_sizes, int n_in,
                              void* d_out, int out_size, void* d_ws, size_t ws_size,
                              hipStream_t stream) {
  const float* pts = (const float*)d_in[0];
  const float* feat = (const float*)d_in[1];
  const float* w0 = (const float*)d_in[2];
  const float* g0 = (const float*)d_in[3];
  const float* b0 = (const float*)d_in[4];
  const float* m0 = (const float*)d_in[5];
  const float* v0 = (const float*)d_in[6];
  const float* w1 = (const float*)d_in[7];
  const float* g1 = (const float*)d_in[8];
  const float* b1 = (const float*)d_in[9];
  const float* m1 = (const float*)d_in[10];
  const float* v1 = (const float*)d_in[11];
  const float* w2 = (const float*)d_in[12];
  const float* g2 = (const float*)d_in[13];
  const float* b2 = (const float*)d_in[14];
  const float* m2 = (const float*)d_in[15];
  const float* v2 = (const float*)d_in[16];
  const float* wsc = (const float*)d_in[17];
  const float* gsc = (const float*)d_in[18];
  const float* bsc = (const float*)d_in[19];
  const float* msc = (const float*)d_in[20];
  const float* vsc = (const float*)d_in[21];
  float* out = (float*)d_out;

  (void)d_ws; (void)ws_size;  // unused: knn indices stashed in d_out

  int* knn = (int*)d_out;  // block i's 1024 indices at out[i*4096..]

  knn_kernel<<<dim3(1024), dim3(256), 0, stream>>>(pts, knn);
  mlp_kernel<<<dim3(512), dim3(256), 0, stream>>>(
      feat, knn, w0, g0, b0, m0, v0, w1, g1, b1, m1, v1, w2, g2, b2, m2, v2,
      wsc, gsc, bsc, msc, vsc, out);
}

// Round 14
// 169.985 us; speedup vs baseline: 1.0170x; 1.0170x over previous
//
#include <hip/hip_runtime.h>
#include <stdint.h>

// EdgeConv B=256,N=128,C=64,K=16 — FINAL: best verified kernel (R12, 171.0us).
// Session summary: mlp 53.9 -> 41.9us (layer0 algebraic split: x@W0 =
// center@(Wtop-Wbot) + nbr@Wbot with per-wave center GEMM + shfl broadcast;
// hw v_cvt_pk_bf16_f32 packs; knn-idx preload; depth-1 neighbor prefetch;
// 2-row ILP pipeline sharing weight B-fragments). knn = validated rank-count
// (exact-tie u64 keys). Indices stashed in d_out (no d_ws) — proved the
// 268MB harness poison-fills (~84us, 80% HBM peak) are unconditional.
// Fused knn+mlp attempted 3x (R9/R10/R14): deterministic absmax ~0.22 with
// both halves individually validated; undiagnosable here — abandoned.
// Remaining mlp regime: latency-bound (MfmaUtil 12%, Occ 17%).

#define KK 16
#define EPSV 1e-3f
#define SW0 136  // w0T stride (128 k-cols + 8 pad, ushorts)
#define SW 72    // 64 + 8

typedef __bf16 bf16x8 __attribute__((ext_vector_type(8)));
typedef float f32x4 __attribute__((ext_vector_type(4)));
union B8 { uint4 u; bf16x8 v; };

__device__ __forceinline__ unsigned int f2ord(float f) {
  unsigned int u = __float_as_uint(f);
  return (u & 0x80000000u) ? ~u : (u | 0x80000000u);
}
__device__ __forceinline__ unsigned short f2bs(float f) {
  __bf16 b = (__bf16)f;  // RNE fptrunc
  return __builtin_bit_cast(unsigned short, b);
}
__device__ __forceinline__ unsigned int pk(float lo, float hi) {
  return (unsigned int)f2bs(lo) | ((unsigned int)f2bs(hi) << 16);
}

__global__ __launch_bounds__(256) void knn_kernel(const float* __restrict__ pts,
                                                  int* __restrict__ knn) {
  __shared__ __align__(16) unsigned long long keys[4][128];
  const int wv = threadIdx.x >> 6;
  const int lane = threadIdx.x & 63;
  const int row = blockIdx.x * 4 + wv;
  const int b = row >> 7;
  const int n = row & 127;
  const float2* pb = (const float2*)(pts + b * 128 * 2);
  const float2 pn = pb[n];
  const float rn = __fadd_rn(__fmul_rn(pn.x, pn.x), __fmul_rn(pn.y, pn.y));

  unsigned long long key0, key1;
#pragma unroll
  for (int h = 0; h < 2; ++h) {
    const int j = lane + h * 64;
    const float2 pj = pb[j];
    const float rj = __fadd_rn(__fmul_rn(pj.x, pj.x), __fmul_rn(pj.y, pj.y));
    const float dot = __fadd_rn(__fmul_rn(pn.x, pj.x), __fmul_rn(pn.y, pj.y));
    const float d = __fadd_rn(__fsub_rn(rn, __fmul_rn(2.0f, dot)), rj);
    unsigned long long k = ((unsigned long long)f2ord(d) << 32) | (unsigned int)j;
    if (h == 0) key0 = k; else key1 = k;
  }
  keys[wv][lane] = key0;
  keys[wv][lane + 64] = key1;
  // in-wave DS ordering: writes above complete before reads below (same wave)
  int c0 = 0, c1 = 0;
#pragma unroll 8
  for (int j = 0; j < 128; j += 2) {
    const ulonglong2 kp = *(const ulonglong2*)&keys[wv][j];
    c0 += (kp.x < key0); c0 += (kp.y < key0);
    c1 += (kp.x < key1); c1 += (kp.y < key1);
  }
  // out-stash layout: block (row>>6)'s region, slot (row&63)*KK + rank-1
  const int base = (row >> 6) * 4096 + (row & 63) * KK;
  if (c0 >= 1 && c0 <= 16) knn[base + c0 - 1] = lane;
  if (c1 >= 1 && c1 <= 16) knn[base + c1 - 1] = lane + 64;
}

__global__ __launch_bounds__(256) void mlp_kernel(
    const float* __restrict__ feat, const int* knnIdx,
    const float* __restrict__ w0, const float* __restrict__ g0,
    const float* __restrict__ b0, const float* __restrict__ m0,
    const float* __restrict__ v0, const float* __restrict__ w1,
    const float* __restrict__ g1, const float* __restrict__ b1,
    const float* __restrict__ m1, const float* __restrict__ v1,
    const float* __restrict__ w2, const float* __restrict__ g2,
    const float* __restrict__ b2, const float* __restrict__ m2,
    const float* __restrict__ v2, const float* __restrict__ wsc,
    const float* __restrict__ gsc, const float* __restrict__ bsc,
    const float* __restrict__ msc, const float* __restrict__ vsc,
    float* out) {
  __shared__ __align__(16) unsigned short w0T[64 * SW0];   // [cout][cin] bf16
  __shared__ __align__(16) unsigned short w1T[64 * SW];
  __shared__ __align__(16) unsigned short w2T[64 * SW];
  __shared__ __align__(16) unsigned short wscT[64 * SW];
  __shared__ __align__(16) unsigned short X0[4][2][16 * SW];  // 2 tiles/wave

  const int tid = threadIdx.x;
  const int wv = tid >> 6;       // 4 waves
  const int lane = tid & 63;
  const int m = lane & 15;   // MFMA m/n within tile
  const int q4 = lane >> 4;  // MFMA quad

  // ---- preload knn indices for all 16 rows (from this block's out region;
  //      issued before __syncthreads so loads drain before any out store) ----
  const int row0 = blockIdx.x * 64 + wv * 16;  // this wave's 16 rows
  const int kk = lane >> 2, pp = lane & 3;
  int jdx[16];
#pragma unroll
  for (int rr = 0; rr < 16; ++rr)
    jdx[rr] = knnIdx[blockIdx.x * 4096 + (wv * 16 + rr) * KK + kk];

  // ---- stage weights transposed to bf16 (once per block) ----
#pragma unroll
  for (int q = 0; q < 8; ++q) {
    const int v = tid + 256 * q;           // float4 idx, 2048 total
    const float4 w = ((const float4*)w0)[v];
    const int i = v >> 4, c = (v & 15) << 2;
    w0T[(c + 0) * SW0 + i] = f2bs(w.x);
    w0T[(c + 1) * SW0 + i] = f2bs(w.y);
    w0T[(c + 2) * SW0 + i] = f2bs(w.z);
    w0T[(c + 3) * SW0 + i] = f2bs(w.w);
  }
#pragma unroll
  for (int q = 0; q < 4; ++q) {
    const int v = tid + 256 * q;           // 1024 total each
    const int i = v >> 4, c = (v & 15) << 2;
    float4 w = ((const float4*)w1)[v];
    w1T[(c + 0) * SW + i] = f2bs(w.x);
    w1T[(c + 1) * SW + i] = f2bs(w.y);
    w1T[(c + 2) * SW + i] = f2bs(w.z);
    w1T[(c + 3) * SW + i] = f2bs(w.w);
    w = ((const float4*)w2)[v];
    w2T[(c + 0) * SW + i] = f2bs(w.x);
    w2T[(c + 1) * SW + i] = f2bs(w.y);
    w2T[(c + 2) * SW + i] = f2bs(w.z);
    w2T[(c + 3) * SW + i] = f2bs(w.w);
    w = ((const float4*)wsc)[v];
    wscT[(c + 0) * SW + i] = f2bs(w.x);
    wscT[(c + 1) * SW + i] = f2bs(w.y);
    wscT[(c + 2) * SW + i] = f2bs(w.z);
    wscT[(c + 3) * SW + i] = f2bs(w.w);
  }

  // ---- folded BN affine, this lane's channel per n-tile: c = nt*16+m ----
  float s0[4], o0[4], s1[4], o1[4], s2[4], o2[4], ssc[4], osc[4];
#pragma unroll
  for (int nt = 0; nt < 4; ++nt) {
    const int c = nt * 16 + m;
    float s;
    s = g0[c] / sqrtf(v0[c] + EPSV); s0[nt] = s; o0[nt] = b0[c] - m0[c] * s;
    s = g1[c] / sqrtf(v1[c] + EPSV); s1[nt] = s; o1[nt] = b1[c] - m1[c] * s;
    s = g2[c] / sqrtf(v2[c] + EPSV); s2[nt] = s; o2[nt] = b2[c] - m2[c] * s;
    s = gsc[c] / sqrtf(vsc[c] + EPSV); ssc[nt] = s; osc[nt] = bsc[c] - msc[c] * s;
  }

  // ---- stage this wave's 16 center rows as bf16 into X0[wv][0] ----
  {
    const int r = lane >> 2, p = lane & 3;
    const float4* fr = (const float4*)(feat + (row0 + r) * 64);
    const float4 a = fr[p * 4 + 0], bq = fr[p * 4 + 1];
    const float4 cq = fr[p * 4 + 2], dq = fr[p * 4 + 3];
    uint4 u0, u1;
    u0.x = pk(a.x, a.y); u0.y = pk(a.z, a.w);
    u0.z = pk(bq.x, bq.y); u0.w = pk(bq.z, bq.w);
    u1.x = pk(cq.x, cq.y); u1.y = pk(cq.z, cq.w);
    u1.z = pk(dq.x, dq.y); u1.w = pk(dq.z, dq.w);
    *(uint4*)&X0[wv][0][r * SW + p * 16] = u0;
    *(uint4*)&X0[wv][0][r * SW + p * 16 + 8] = u1;
  }

  const float* featb = feat + (row0 >> 7) * (128 * 64);  // batch base

  // ---- prefetch rows 0,1 neighbor features (packed to bf16 on arrival) ----
  uint4 uA0, uA1, uB0, uB1;
  {
    const float4* np_ = (const float4*)(featb + jdx[0] * 64);
    const float4 n0 = np_[pp * 4 + 0], n1 = np_[pp * 4 + 1];
    const float4 n2 = np_[pp * 4 + 2], n3 = np_[pp * 4 + 3];
    uA0.x = pk(n0.x, n0.y); uA0.y = pk(n0.z, n0.w);
    uA0.z = pk(n1.x, n1.y); uA0.w = pk(n1.z, n1.w);
    uA1.x = pk(n2.x, n2.y); uA1.y = pk(n2.z, n2.w);
    uA1.z = pk(n3.x, n3.y); uA1.w = pk(n3.z, n3.w);
  }
  {
    const float4* np_ = (const float4*)(featb + jdx[1] * 64);
    const float4 n0 = np_[pp * 4 + 0], n1 = np_[pp * 4 + 1];
    const float4 n2 = np_[pp * 4 + 2], n3 = np_[pp * 4 + 3];
    uB0.x = pk(n0.x, n0.y); uB0.y = pk(n0.z, n0.w);
    uB0.z = pk(n1.x, n1.y); uB0.w = pk(n1.z, n1.w);
    uB1.x = pk(n2.x, n2.y); uB1.y = pk(n2.z, n2.w);
    uB1.z = pk(n3.x, n3.y); uB1.w = pk(n3.z, n3.w);
  }

  __syncthreads();  // weights visible; all waves' jdx loads drained

  // ---- prelim GEMMs over centers: shortcut (wsc), w0-top, w0-bot ----
  const f32x4 fzero = {0.f, 0.f, 0.f, 0.f};
  f32x4 sacc[4] = {fzero, fzero, fzero, fzero};
  f32x4 ctp[4] = {fzero, fzero, fzero, fzero};
  f32x4 cbt[4] = {fzero, fzero, fzero, fzero};
#pragma unroll
  for (int t = 0; t < 2; ++t) {
    B8 af; af.u = *(const uint4*)&X0[wv][0][m * SW + t * 32 + q4 * 8];
#pragma unroll
    for (int nt = 0; nt < 4; ++nt) {
      B8 bs, bt, bb;
      bs.u = *(const uint4*)&wscT[(nt * 16 + m) * SW + t * 32 + q4 * 8];
      bt.u = *(const uint4*)&w0T[(nt * 16 + m) * SW0 + t * 32 + q4 * 8];
      bb.u = *(const uint4*)&w0T[(nt * 16 + m) * SW0 + 64 + t * 32 + q4 * 8];
      sacc[nt] = __builtin_amdgcn_mfma_f32_16x16x32_bf16(af.v, bs.v, sacc[nt], 0, 0, 0);
      ctp[nt]  = __builtin_amdgcn_mfma_f32_16x16x32_bf16(af.v, bt.v, ctp[nt], 0, 0, 0);
      cbt[nt]  = __builtin_amdgcn_mfma_f32_16x16x32_bf16(af.v, bb.v, cbt[nt], 0, 0, 0);
    }
  }
  // scf: BN'd shortcut; ct: center@(Wtop-Wbot), row = q4*4+reg, ch = nt*16+m
  float scf[4][4], ct[4][4];
#pragma unroll
  for (int nt = 0; nt < 4; ++nt)
#pragma unroll
    for (int r = 0; r < 4; ++r) {
      scf[nt][r] = fmaf(sacc[nt][r], ssc[nt], osc[nt]);
      ct[nt][r] = ctp[nt][r] - cbt[nt][r];
    }

  // ---- 8 iterations x 2 rows (static reg indexing throughout) ----
#pragma unroll
  for (int rp = 0; rp < 8; ++rp) {
    const int qo = rp >> 1;                 // = rowA>>2 = rowB>>2
    const int riA = (2 * rp) & 3, riB = (2 * rp + 1) & 3;
    const int rowA = row0 + 2 * rp, rowB = rowA + 1;

    // stage both rows' neighbors (prefetched, already bf16-packed)
    *(uint4*)&X0[wv][0][kk * SW + pp * 16] = uA0;
    *(uint4*)&X0[wv][0][kk * SW + pp * 16 + 8] = uA1;
    *(uint4*)&X0[wv][1][kk * SW + pp * 16] = uB0;
    *(uint4*)&X0[wv][1][kk * SW + pp * 16 + 8] = uB1;

    // prefetch next row pair (hidden under this pair's MFMAs)
    if (rp < 7) {
      {
        const float4* np_ = (const float4*)(featb + jdx[2 * rp + 2] * 64);
        const float4 n0 = np_[pp * 4 + 0], n1 = np_[pp * 4 + 1];
        const float4 n2 = np_[pp * 4 + 2], n3 = np_[pp * 4 + 3];
        uA0.x = pk(n0.x, n0.y); uA0.y = pk(n0.z, n0.w);
        uA0.z = pk(n1.x, n1.y); uA0.w = pk(n1.z, n1.w);
        uA1.x = pk(n2.x, n2.y); uA1.y = pk(n2.z, n2.w);
        uA1.z = pk(n3.x, n3.y); uA1.w = pk(n3.z, n3.w);
      }
      {
        const float4* np_ = (const float4*)(featb + jdx[2 * rp + 3] * 64);
        const float4 n0 = np_[pp * 4 + 0], n1 = np_[pp * 4 + 1];
        const float4 n2 = np_[pp * 4 + 2], n3 = np_[pp * 4 + 3];
        uB0.x = pk(n0.x, n0.y); uB0.y = pk(n0.z, n0.w);
        uB0.z = pk(n1.x, n1.y); uB0.w = pk(n1.z, n1.w);
        uB1.x = pk(n2.x, n2.y); uB1.y = pk(n2.z, n2.w);
        uB1.z = pk(n3.x, n3.y); uB1.w = pk(n3.z, n3.w);
      }
    }

    // ---- layer 0: acc = centerTerm(row) + nbr @ w0_bot (K=64) ----
    f32x4 accA[4], accB[4];
#pragma unroll
    for (int nt = 0; nt < 4; ++nt) {
      const float cA = __shfl(ct[nt][riA], qo * 16 + m);
      const float cB = __shfl(ct[nt][riB], qo * 16 + m);
      f32x4 a; a[0] = cA; a[1] = cA; a[2] = cA; a[3] = cA;
      accA[nt] = a;
      f32x4 b; b[0] = cB; b[1] = cB; b[2] = cB; b[3] = cB;
      accB[nt] = b;
    }
#pragma unroll
    for (int t = 0; t < 2; ++t) {
      B8 afA, afB;
      afA.u = *(const uint4*)&X0[wv][0][m * SW + t * 32 + q4 * 8];
      afB.u = *(const uint4*)&X0[wv][1][m * SW + t * 32 + q4 * 8];
#pragma unroll
      for (int nt = 0; nt < 4; ++nt) {
        B8 bf_; bf_.u = *(const uint4*)&w0T[(nt * 16 + m) * SW0 + 64 + t * 32 + q4 * 8];
        accA[nt] = __builtin_amdgcn_mfma_f32_16x16x32_bf16(afA.v, bf_.v, accA[nt], 0, 0, 0);
        accB[nt] = __builtin_amdgcn_mfma_f32_16x16x32_bf16(afB.v, bf_.v, accB[nt], 0, 0, 0);
      }
    }
#pragma unroll
    for (int nt = 0; nt < 4; ++nt)
#pragma unroll
      for (int r2 = 0; r2 < 4; ++r2) {
        const float yA = fmaxf(fmaf(accA[nt][r2], s0[nt], o0[nt]), 0.f);
        const float yB = fmaxf(fmaf(accB[nt][r2], s0[nt], o0[nt]), 0.f);
        X0[wv][0][(q4 * 4 + r2) * SW + nt * 16 + m] = f2bs(yA);
        X0[wv][1][(q4 * 4 + r2) * SW + nt * 16 + m] = f2bs(yB);
      }

    // ---- layer 1: K=64 (in-place, in-wave DS ordering) ----
#pragma unroll
    for (int nt = 0; nt < 4; ++nt) { accA[nt] = fzero; accB[nt] = fzero; }
#pragma unroll
    for (int t = 0; t < 2; ++t) {
      B8 afA, afB;
      afA.u = *(const uint4*)&X0[wv][0][m * SW + t * 32 + q4 * 8];
      afB.u = *(const uint4*)&X0[wv][1][m * SW + t * 32 + q4 * 8];
#pragma unroll
      for (int nt = 0; nt < 4; ++nt) {
        B8 bf_; bf_.u = *(const uint4*)&w1T[(nt * 16 + m) * SW + t * 32 + q4 * 8];
        accA[nt] = __builtin_amdgcn_mfma_f32_16x16x32_bf16(afA.v, bf_.v, accA[nt], 0, 0, 0);
        accB[nt] = __builtin_amdgcn_mfma_f32_16x16x32_bf16(afB.v, bf_.v, accB[nt], 0, 0, 0);
      }
    }
#pragma unroll
    for (int nt = 0; nt < 4; ++nt)
#pragma unroll
      for (int r2 = 0; r2 < 4; ++r2) {
        const float yA = fmaxf(fmaf(accA[nt][r2], s1[nt], o1[nt]), 0.f);
        const float yB = fmaxf(fmaf(accB[nt][r2], s1[nt], o1[nt]), 0.f);
        X0[wv][0][(q4 * 4 + r2) * SW + nt * 16 + m] = f2bs(yA);
        X0[wv][1][(q4 * 4 + r2) * SW + nt * 16 + m] = f2bs(yB);
      }

    // ---- layer 2: K=64 ----
#pragma unroll
    for (int nt = 0; nt < 4; ++nt) { accA[nt] = fzero; accB[nt] = fzero; }
#pragma unroll
    for (int t = 0; t < 2; ++t) {
      B8 afA, afB;
      afA.u = *(const uint4*)&X0[wv][0][m * SW + t * 32 + q4 * 8];
      afB.u = *(const uint4*)&X0[wv][1][m * SW + t * 32 + q4 * 8];
#pragma unroll
      for (int nt = 0; nt < 4; ++nt) {
        B8 bf_; bf_.u = *(const uint4*)&w2T[(nt * 16 + m) * SW + t * 32 + q4 * 8];
        accA[nt] = __builtin_amdgcn_mfma_f32_16x16x32_bf16(afA.v, bf_.v, accA[nt], 0, 0, 0);
        accB[nt] = __builtin_amdgcn_mfma_f32_16x16x32_bf16(afB.v, bf_.v, accB[nt], 0, 0, 0);
      }
    }

    // ---- BN+ReLU, mean over k, add shortcut, store both rows ----
    float poolA[4], poolB[4];
#pragma unroll
    for (int nt = 0; nt < 4; ++nt) {
      float pa = 0.f, pb2 = 0.f;
#pragma unroll
      for (int r2 = 0; r2 < 4; ++r2) {
        pa += fmaxf(fmaf(accA[nt][r2], s2[nt], o2[nt]), 0.f);
        pb2 += fmaxf(fmaf(accB[nt][r2], s2[nt], o2[nt]), 0.f);
      }
      pa += __shfl_xor(pa, 16);
      pa += __shfl_xor(pa, 32);
      poolA[nt] = pa * 0.0625f;
      pb2 += __shfl_xor(pb2, 16);
      pb2 += __shfl_xor(pb2, 32);
      poolB[nt] = pb2 * 0.0625f;
    }
    if (q4 == qo) {
#pragma unroll
      for (int nt = 0; nt < 4; ++nt) {
        out[rowA * 64 + nt * 16 + m] = fmaxf(scf[nt][riA] + poolA[nt], 0.f);
        out[rowB * 64 + nt * 16 + m] = fmaxf(scf[nt][riB] + poolB[nt], 0.f);
      }
    }
  }
}

extern "C" void kernel_launch(void* const* d_in, const int* in_sizes, int n_in,
                              void* d_out, int out_size, void* d_ws, size_t ws_size,
                              hipStream_t stream) {
  const float* pts = (const float*)d_in[0];
  const float* feat = (const float*)d_in[1];
  const float* w0 = (const float*)d_in[2];
  const float* g0 = (const float*)d_in[3];
  const float* b0 = (const float*)d_in[4];
  const float* m0 = (const float*)d_in[5];
  const float* v0 = (const float*)d_in[6];
  const float* w1 = (const float*)d_in[7];
  const float* g1 = (const float*)d_in[8];
  const float* b1 = (const float*)d_in[9];
  const float* m1 = (const float*)d_in[10];
  const float* v1 = (const float*)d_in[11];
  const float* w2 = (const float*)d_in[12];
  const float* g2 = (const float*)d_in[13];
  const float* b2 = (const float*)d_in[14];
  const float* m2 = (const float*)d_in[15];
  const float* v2 = (const float*)d_in[16];
  const float* wsc = (const float*)d_in[17];
  const float* gsc = (const float*)d_in[18];
  const float* bsc = (const float*)d_in[19];
  const float* msc = (const float*)d_in[20];
  const float* vsc = (const float*)d_in[21];
  float* out = (float*)d_out;

  (void)d_ws; (void)ws_size;  // unused: knn indices stashed in d_out

  int* knn = (int*)d_out;  // block i's 1024 indices at out[i*4096..]

  knn_kernel<<<dim3(256 * 128 / 4), dim3(256), 0, stream>>>(pts, knn);
  mlp_kernel<<<dim3(512), dim3(256), 0, stream>>>(
      feat, knn, w0, g0, b0, m0, v0, w1, g1, b1, m1, v1, w2, g2, b2, m2, v2,
      wsc, gsc, bsc, msc, vsc, out);
}